// Round 3
// baseline (1028.280 us; speedup 1.0000x reference)
//
#include <hip/hip_runtime.h>

// TensorProductWithScalarComponents: out[s,w',k] = c * sum_{u,v} Wc[(u,v),w'] * x[s,u,k]*y[s,v]
// Wc = Wt . Wl folded on device per launch, packed in MFMA-B fragment order (f16).
// One GEMM per irrep block (l=0,1,2), A built on the fly (outer product) via v_pk_mul_f16,
// f16 MFMA 16x16x32. Path-norm scale (exact pow2) applied in the f32 epilogue.

typedef _Float16 f16x8 __attribute__((ext_vector_type(8)));
typedef _Float16 h2    __attribute__((ext_vector_type(2)));
typedef float    f32x4 __attribute__((ext_vector_type(4)));

// ---------------- prologue: fold Wl into Wt, pack into MFMA-B fragment layout (f16) ----------
// Packed element (kc, nt, lane, j) <-> (u = kc%M, vh = kc/M, v = vh*32 + (lane>>4)*8 + j,
//                                       w' = nt*16 + (lane&15))
// stored at Bp[((kc*NT + nt)*64 + lane)*8 + j]   (K-order: vh outer, u inner)
template<int M, int NT>
__global__ void pack_b(const float* __restrict__ Wt, const float* __restrict__ Wl,
                       _Float16* __restrict__ Bp) {
    const int gid = blockIdx.x * 256 + threadIdx.x;
    const int total = M * 64 * M;            // (u,v) x w'
    if (gid >= total) return;
    const int w_ = gid & (M - 1);            // output channel w'
    const int uv = gid / M;
    const int u = uv >> 6, v = uv & 63;
    const float4* wt4 = (const float4*)(Wt + (size_t)uv * M);
    float acc = 0.f;
    #pragma unroll 4
    for (int w = 0; w < M; w += 4) {
        float4 t = wt4[w >> 2];
        acc += t.x * Wl[(w + 0) * M + w_] + t.y * Wl[(w + 1) * M + w_]
             + t.z * Wl[(w + 2) * M + w_] + t.w * Wl[(w + 3) * M + w_];
    }
    const int vh = v >> 5, vv = v & 31, quad = vv >> 3, j = vv & 7;
    const int kc = vh * M + u, nt = w_ >> 4, lane = quad * 16 + (w_ & 15);
    Bp[((size_t)(kc * NT + nt) * 64 + lane) * 8 + j] = (_Float16)acc;
}

// ---------------- main fused GEMM ----------------
template<int M, int NCOMP, int XOFF, int NT, int MT, int WAVES_N, int LOGM>
__device__ __forceinline__ void tp_block(char* smem, int wg,
    const float* __restrict__ x, const float* __restrict__ y,
    const _Float16* __restrict__ Bp, float* __restrict__ out, int Rtot, float cscale)
{
    constexpr int YS = 80;            // y LDS row stride (f16), 16B-aligned rows
    constexpr int XS = MT + 8;        // x LDS row stride: breaks 64-way staging-write conflict
    constexpr int WAVES_M = 4 / WAVES_N;
    constexpr int WM = (MT / 16) / WAVES_M;   // m-frags per wave
    constexpr int WN = NT / WAVES_N;          // B-frags per wave

    _Float16* xr = (_Float16*)smem;                       // [M][XS]
    _Float16* yl = (_Float16*)(smem + M * XS * 2);        // [MT][YS]
    const int tid = threadIdx.x;
    const int r0 = wg * MT;

    // stage x transposed (f16): xr[u][row] = x[s(row), XOFF + u*NCOMP + k(row)]
    for (int idx = tid; idx < M * MT; idx += 256) {
        const int u = idx & (M - 1);
        const int row = idx >> LOGM;
        const int R = r0 + row;
        float v = 0.f;
        if (R < Rtot) {
            const int s = R / NCOMP;
            const int k = R - s * NCOMP;
            v = x[(size_t)s * 480 + XOFF + u * NCOMP + k];
        }
        xr[u * XS + row] = (_Float16)v;
    }
    // stage y per-row (duplicated across k-components of a sample), f16
    for (int idx = tid; idx < MT * 64; idx += 256) {
        const int v_ = idx & 63;
        const int row = idx >> 6;
        const int R = r0 + row;
        float val = 0.f;
        if (R < Rtot) { const int s = R / NCOMP; val = y[(size_t)s * 64 + v_]; }
        yl[row * YS + v_] = (_Float16)val;
    }
    __syncthreads();

    const int lane = tid & 63;
    const int wv = tid >> 6;
    const int wni = wv % WAVES_N;
    const int wmi = wv / WAVES_N;
    const int l15 = lane & 15;
    const int quad = lane >> 4;

    int rowf[WM];
    #pragma unroll
    for (int f = 0; f < WM; ++f) rowf[f] = (wmi * WM + f) * 16 + l15;

    f32x4 acc[WM][WN];
    #pragma unroll
    for (int f = 0; f < WM; ++f)
        #pragma unroll
        for (int g = 0; g < WN; ++g) acc[f][g] = f32x4{0.f, 0.f, 0.f, 0.f};

    const unsigned short* xs16 = (const unsigned short*)xr;  // raw f16 bits
    const _Float16* ys16 = yl;
    const f16x8* bbase = (const f16x8*)Bp;   // fragment index = (kc*NT+nt)*64+lane

    f16x8 bcur[WN];
    unsigned short xcur[WM];
    #pragma unroll
    for (int g = 0; g < WN; ++g) bcur[g] = bbase[(0 * NT + wni * WN + g) * 64 + lane];
    #pragma unroll
    for (int f = 0; f < WM; ++f) xcur[f] = xs16[0 * XS + rowf[f]];

    union Yf { uint4 u4; h2 h[4]; };
    Yf yh[WM];

    #pragma unroll 2
    for (int kc = 0; kc < 2 * M; ++kc) {
        const int u = kc & (M - 1);
        if (u == 0) {  // (re)load y fragments for this v-half; packed f16 pairs, no unpack
            const int vh = kc >> LOGM;
            #pragma unroll
            for (int f = 0; f < WM; ++f)
                yh[f].u4 = *(const uint4*)(ys16 + rowf[f] * YS + vh * 32 + quad * 8);
        }
        // prefetch next chunk's B fragments (global/L2) and x scalars (LDS)
        f16x8 bnxt[WN];
        unsigned short xnxt[WM];
        if (kc + 1 < 2 * M) {
            const int kn = kc + 1, un = kn & (M - 1);
            #pragma unroll
            for (int g = 0; g < WN; ++g) bnxt[g] = bbase[(kn * NT + wni * WN + g) * 64 + lane];
            #pragma unroll
            for (int f = 0; f < WM; ++f) xnxt[f] = xs16[un * XS + rowf[f]];
        }
        // build A fragments: a[j] = x[s,u,k] * y[s, vh*32 + quad*8 + j]  (v_pk_mul_f16 x4)
        f16x8 af[WM];
        #pragma unroll
        for (int f = 0; f < WM; ++f) {
            unsigned t = (unsigned)xcur[f];
            t |= t << 16;                        // broadcast f16 -> half2 (v_lshl_or_b32)
            union { unsigned u; h2 h; } xb_; xb_.u = t;
            union { f16x8 v8; h2 h[4]; } u_;
            #pragma unroll
            for (int j = 0; j < 4; ++j) u_.h[j] = xb_.h * yh[f].h[j];
            af[f] = u_.v8;
        }
        #pragma unroll
        for (int f = 0; f < WM; ++f)
            #pragma unroll
            for (int g = 0; g < WN; ++g)
                acc[f][g] = __builtin_amdgcn_mfma_f32_16x16x32_f16(af[f], bcur[g], acc[f][g], 0, 0, 0);
        if (kc + 1 < 2 * M) {
            #pragma unroll
            for (int g = 0; g < WN; ++g) bcur[g] = bnxt[g];
            #pragma unroll
            for (int f = 0; f < WM; ++f) xcur[f] = xnxt[f];
        }
    }

    // epilogue: C/D layout col = lane&15, row = quad*4 + reg (m89-verified); apply pow2 scale
    #pragma unroll
    for (int f = 0; f < WM; ++f) {
        #pragma unroll
        for (int g = 0; g < WN; ++g) {
            const int col = (wni * WN + g) * 16 + l15;   // w'
            #pragma unroll
            for (int r = 0; r < 4; ++r) {
                const int R = r0 + (wmi * WM + f) * 16 + quad * 4 + r;
                if (R < Rtot) {
                    const int s = R / NCOMP;
                    const int k = R - s * NCOMP;
                    out[(size_t)s * 480 + XOFF + col * NCOMP + k] = acc[f][g][r] * cscale;
                }
            }
        }
    }
}

__global__ __launch_bounds__(256, 2)
void tp_main(const float* __restrict__ x, const float* __restrict__ y,
             const _Float16* __restrict__ B0, const _Float16* __restrict__ B1,
             const _Float16* __restrict__ B2, float* __restrict__ out,
             int R0, int R1, int R2, int G0, int G1)
{
    __shared__ char smem[57856];   // max over the three block configs
    const int b = blockIdx.x;
    if (b < G0)            tp_block<128, 1,   0, 8, 128, 2, 7>(smem, b,           x, y, B0, out, R0, 1.f / 1024.f);
    else if (b < G0 + G1)  tp_block< 64, 3, 128, 4, 128, 2, 6>(smem, b - G0,      x, y, B1, out, R1, 1.f / 512.f);
    else                   tp_block< 32, 5, 320, 2, 256, 1, 5>(smem, b - G0 - G1, x, y, B2, out, R2, 1.f / 256.f);
}

extern "C" void kernel_launch(void* const* d_in, const int* in_sizes, int n_in,
                              void* d_out, int out_size, void* d_ws, size_t ws_size,
                              hipStream_t stream) {
    const float* x   = (const float*)d_in[0];
    const float* y   = (const float*)d_in[1];
    const float* Wt0 = (const float*)d_in[2];
    const float* Wl0 = (const float*)d_in[3];
    const float* Wt1 = (const float*)d_in[4];
    const float* Wl1 = (const float*)d_in[5];
    const float* Wt2 = (const float*)d_in[6];
    const float* Wl2 = (const float*)d_in[7];
    float* out = (float*)d_out;

    const int Ns = in_sizes[0] / 480;

    _Float16* B0 = (_Float16*)d_ws;                    // 8192x128 f16 = 2 MiB
    _Float16* B1 = B0 + 8192 * 128;                    // 4096x64  = 512 KiB
    _Float16* B2 = B1 + 4096 * 64;                     // 2048x32  = 128 KiB

    pack_b<128, 8><<<(128 * 64 * 128 + 255) / 256, 256, 0, stream>>>(Wt0, Wl0, B0);
    pack_b< 64, 4><<<( 64 * 64 *  64 + 255) / 256, 256, 0, stream>>>(Wt1, Wl1, B1);
    pack_b< 32, 2><<<( 32 * 64 *  32 + 255) / 256, 256, 0, stream>>>(Wt2, Wl2, B2);

    const int R0 = Ns, R1 = Ns * 3, R2 = Ns * 5;
    const int G0 = (R0 + 127) / 128;
    const int G1 = (R1 + 127) / 128;
    const int G2 = (R2 + 255) / 256;
    tp_main<<<G0 + G1 + G2, 256, 0, stream>>>(x, y, B0, B1, B2, out, R0, R1, R2, G0, G1);
}

// Round 4
// 818.460 us; speedup vs baseline: 1.2564x; 1.2564x over previous
//
#include <hip/hip_runtime.h>

// TensorProductWithScalarComponents: out[s,w',k] = c * sum_{u,v} Wc[(u,v),w'] * x[s,u,k]*y[s,v]
// Wc = Wt . Wl folded on device, packed in MFMA-B fragment order (f16).
// One GEMM per irrep block (l=0,1,2); A built on the fly via v_pk_mul_f16; f16 MFMA 16x16x32.
// Latency-oriented: 3 blocks/CU (per-sample y LDS + swizzled unpadded x LDS),
// x read 8-kc-batched via ds_read_b128, B double-ring prefetch (distance 2).

typedef _Float16 f16x8 __attribute__((ext_vector_type(8)));
typedef _Float16 h2    __attribute__((ext_vector_type(2)));
typedef float    f32x4 __attribute__((ext_vector_type(4)));

// ---------------- prologue: fold Wl into Wt, pack into MFMA-B fragment layout (f16) ----------
// Packed element (kc, nt, lane, j) <-> (u = kc%M, vh = kc/M, v = vh*32 + (lane>>4)*8 + j,
//                                       w' = nt*16 + (lane&15))
// stored at Bp[((kc*NT + nt)*64 + lane)*8 + j]   (K-order: vh outer, u inner)
// Each thread computes 2 adjacent uv rows (shares Wl column loads).
template<int M, int NT>
__global__ void pack_b(const float* __restrict__ Wt, const float* __restrict__ Wl,
                       _Float16* __restrict__ Bp) {
    const int gid = blockIdx.x * 256 + threadIdx.x;
    const int total = M * 64 * M / 2;
    if (gid >= total) return;
    const int w_ = gid & (M - 1);            // output channel w'
    const int uvp = gid / M;                 // uv pair index
    const float4* wtA = (const float4*)(Wt + (size_t)(2 * uvp) * M);
    const float4* wtB = (const float4*)(Wt + (size_t)(2 * uvp + 1) * M);
    float a0 = 0.f, a1 = 0.f;
    #pragma unroll 4
    for (int w = 0; w < M; w += 4) {
        float4 tA = wtA[w >> 2], tB = wtB[w >> 2];
        float l0 = Wl[(w + 0) * M + w_], l1 = Wl[(w + 1) * M + w_];
        float l2 = Wl[(w + 2) * M + w_], l3 = Wl[(w + 3) * M + w_];
        a0 += tA.x * l0 + tA.y * l1 + tA.z * l2 + tA.w * l3;
        a1 += tB.x * l0 + tB.y * l1 + tB.z * l2 + tB.w * l3;
    }
    #pragma unroll
    for (int t = 0; t < 2; ++t) {
        const int uv = 2 * uvp + t;
        const int u = uv >> 6, v = uv & 63;
        const int vh = v >> 5, vv = v & 31, quad = vv >> 3, j = vv & 7;
        const int kc = vh * M + u, nt = w_ >> 4, lane = quad * 16 + (w_ & 15);
        Bp[((size_t)(kc * NT + nt) * 64 + lane) * 8 + j] = (_Float16)(t ? a1 : a0);
    }
}

// ---------------- main fused GEMM ----------------
template<int M, int NCOMP, int XOFF, int NT, int MT, int WAVES_N, int LOGM>
__device__ __forceinline__ void tp_block(char* smem, int wg,
    const float* __restrict__ x, const float* __restrict__ y,
    const _Float16* __restrict__ Bp, float* __restrict__ out, int Rtot, float cscale)
{
    constexpr int YS = 80;                        // y LDS row stride (f16), 16B-aligned rows
    constexpr int YROWS = (MT + NCOMP - 2) / NCOMP + 1;  // samples touched by an MT-row tile
    constexpr int KTOT = 2 * M;
    constexpr int SWZ = (2 * M >= 128) ? 8 : (2 * M) / 16; // 16B slots per x row for XOR swizzle
    constexpr int WAVES_M = 4 / WAVES_N;
    constexpr int WM = (MT / 16) / WAVES_M;       // m-frags per wave
    constexpr int WN = NT / WAVES_N;              // B-frags per wave

    char* xb = smem;                              // x: [MT][M] f16, byte ^= (row&(SWZ-1))<<4
    _Float16* yl = (_Float16*)(smem + MT * M * 2);// y: [YROWS][YS] f16 (per sample)
    const int tid = threadIdx.x;
    const int r0 = wg * MT;
    const int s0 = r0 / NCOMP;

    // stage x: xb[row][u] = x[s(row), XOFF + u*NCOMP + k(row)]; contiguous writes per row
    for (int idx = tid; idx < M * MT; idx += 256) {
        const int u = idx & (M - 1);
        const int row = idx >> LOGM;
        const int R = r0 + row;
        float v = 0.f;
        if (R < Rtot) {
            const int s = (unsigned)R / NCOMP;
            const int k = R - s * NCOMP;
            v = x[(size_t)s * 480 + XOFF + u * NCOMP + k];
        }
        const int off = ((row * M + u) * 2) ^ ((row & (SWZ - 1)) << 4);
        *(_Float16*)(xb + off) = (_Float16)v;
    }
    // stage y once per sample (not per row)
    for (int idx = tid; idx < YROWS * 64; idx += 256) {
        const int v_ = idx & 63;
        const int row = idx >> 6;
        const int s = s0 + row;
        float val = 0.f;
        if (s * NCOMP < Rtot) val = y[(size_t)s * 64 + v_];
        yl[row * YS + v_] = (_Float16)val;
    }
    __syncthreads();

    const int lane = tid & 63;
    const int wv = tid >> 6;
    const int wni = wv % WAVES_N;
    const int wmi = wv / WAVES_N;
    const int l15 = lane & 15;
    const int quad = lane >> 4;

    int rowf[WM], xoffb[WM], yoffs[WM];
    #pragma unroll
    for (int f = 0; f < WM; ++f) {
        rowf[f] = (wmi * WM + f) * 16 + l15;
        xoffb[f] = (rowf[f] * M * 2) ^ ((rowf[f] & (SWZ - 1)) << 4);
        const int sloc = (int)((unsigned)(r0 + rowf[f]) / NCOMP) - s0;
        yoffs[f] = sloc * YS + quad * 8;          // shorts; add vh*32 at reload
    }

    f32x4 acc[WM][WN];
    #pragma unroll
    for (int f = 0; f < WM; ++f)
        #pragma unroll
        for (int g = 0; g < WN; ++g) acc[f][g] = f32x4{0.f, 0.f, 0.f, 0.f};

    // B addressing: byte = kc*BSTRIDE + (wni*WN+g)*1024 + lane*16
    const char* bpc = (const char*)Bp;
    constexpr unsigned BSTRIDE = (unsigned)NT * 64 * 16;
    const unsigned lane_b = ((unsigned)(wni * WN) * 64 + lane) * 16;
    const unsigned bmax = (unsigned)(KTOT - 1) * BSTRIDE + lane_b;

    f16x8 bpp[2][WN];
    #pragma unroll
    for (int g = 0; g < WN; ++g) {
        bpp[0][g] = *(const f16x8*)(bpc + lane_b + g * 1024);
        bpp[1][g] = *(const f16x8*)(bpc + BSTRIDE + lane_b + g * 1024);
    }
    unsigned boff = 2 * BSTRIDE + lane_b;

    f16x8 xf[WM];
    uint4  yh[WM];

    #pragma unroll 1
    for (int g8 = 0; g8 < KTOT; g8 += 8) {
        const int u0 = g8 & (M - 1);
        // x for this 8-kc group: one ds_read_b128 per fragment
        #pragma unroll
        for (int f = 0; f < WM; ++f)
            xf[f] = *(const f16x8*)(xb + (xoffb[f] ^ (u0 * 2)));
        if (u0 == 0) {  // new v-half: reload y fragments (packed f16 pairs)
            const int vh = g8 >> LOGM;
            #pragma unroll
            for (int f = 0; f < WM; ++f)
                yh[f] = *(const uint4*)(yl + yoffs[f] + vh * 32);
        }
        #pragma unroll
        for (int j = 0; j < 8; ++j) {
            // build A fragments: a = x[s,u0+j,k] * y[s, vh*32 + quad*8 + 0..7]
            f16x8 af[WM];
            #pragma unroll
            for (int f = 0; f < WM; ++f) {
                const _Float16 xh = xf[f][j];
                h2 xbb; xbb[0] = xh; xbb[1] = xh;
                union { uint4 u4; h2 h[4]; } yv; yv.u4 = yh[f];
                union { f16x8 v8; h2 h[4]; } a_;
                #pragma unroll
                for (int q = 0; q < 4; ++q) a_.h[q] = xbb * yv.h[q];
                af[f] = a_.v8;
            }
            #pragma unroll
            for (int f = 0; f < WM; ++f)
                #pragma unroll
                for (int g = 0; g < WN; ++g)
                    acc[f][g] = __builtin_amdgcn_mfma_f32_16x16x32_f16(af[f], bpp[j & 1][g], acc[f][g], 0, 0, 0);
            // prefetch kc+2 into the parity slot just consumed (distance-2 ring, no copies)
            {
                const unsigned bo = boff < bmax ? boff : bmax;
                #pragma unroll
                for (int g = 0; g < WN; ++g)
                    bpp[j & 1][g] = *(const f16x8*)(bpc + bo + g * 1024);
                boff += BSTRIDE;
            }
        }
    }

    // epilogue: C/D layout col = lane&15, row = quad*4 + reg (m89-verified); pow2 scale in f32
    #pragma unroll
    for (int f = 0; f < WM; ++f) {
        #pragma unroll
        for (int g = 0; g < WN; ++g) {
            const int col = (wni * WN + g) * 16 + l15;   // w'
            #pragma unroll
            for (int r = 0; r < 4; ++r) {
                const int R = r0 + (wmi * WM + f) * 16 + quad * 4 + r;
                if (R < Rtot) {
                    const int s = (unsigned)R / NCOMP;
                    const int k = R - s * NCOMP;
                    out[(size_t)s * 480 + XOFF + col * NCOMP + k] = acc[f][g][r] * cscale;
                }
            }
        }
    }
}

__global__ __launch_bounds__(256, 3)
void tp_main(const float* __restrict__ x, const float* __restrict__ y,
             const _Float16* __restrict__ B0, const _Float16* __restrict__ B1,
             const _Float16* __restrict__ B2, float* __restrict__ out,
             int R0, int R1, int R2, int G0, int G1)
{
    // LDS: l0 = 128*128*2 + 128*80*2 = 53248 (max); l1 = 23424; l2 = 24704. 3 blocks/CU.
    __shared__ char smem[53248];
    const int b = blockIdx.x;
    if (b < G0)            tp_block<128, 1,   0, 8, 128, 2, 7>(smem, b,           x, y, B0, out, R0, 1.f / 1024.f);
    else if (b < G0 + G1)  tp_block< 64, 3, 128, 4, 128, 2, 6>(smem, b - G0,      x, y, B1, out, R1, 1.f / 512.f);
    else                   tp_block< 32, 5, 320, 2, 256, 1, 5>(smem, b - G0 - G1, x, y, B2, out, R2, 1.f / 256.f);
}

extern "C" void kernel_launch(void* const* d_in, const int* in_sizes, int n_in,
                              void* d_out, int out_size, void* d_ws, size_t ws_size,
                              hipStream_t stream) {
    const float* x   = (const float*)d_in[0];
    const float* y   = (const float*)d_in[1];
    const float* Wt0 = (const float*)d_in[2];
    const float* Wl0 = (const float*)d_in[3];
    const float* Wt1 = (const float*)d_in[4];
    const float* Wl1 = (const float*)d_in[5];
    const float* Wt2 = (const float*)d_in[6];
    const float* Wl2 = (const float*)d_in[7];
    float* out = (float*)d_out;

    const int Ns = in_sizes[0] / 480;

    _Float16* B0 = (_Float16*)d_ws;                    // 8192x128 f16 = 2 MiB
    _Float16* B1 = B0 + 8192 * 128;                    // 4096x64  = 512 KiB
    _Float16* B2 = B1 + 4096 * 64;                     // 2048x32  = 128 KiB

    pack_b<128, 8><<<(128 * 64 * 128 / 2 + 255) / 256, 256, 0, stream>>>(Wt0, Wl0, B0);
    pack_b< 64, 4><<<( 64 * 64 *  64 / 2 + 255) / 256, 256, 0, stream>>>(Wt1, Wl1, B1);
    pack_b< 32, 2><<<( 32 * 64 *  32 / 2 + 255) / 256, 256, 0, stream>>>(Wt2, Wl2, B2);

    const int R0 = Ns, R1 = Ns * 3, R2 = Ns * 5;
    const int G0 = (R0 + 127) / 128;
    const int G1 = (R1 + 127) / 128;
    const int G2 = (R2 + 255) / 256;
    tp_main<<<G0 + G1 + G2, 256, 0, stream>>>(x, y, B0, B1, B2, out, R0, R1, R2, G0, G1);
}

// Round 6
// 682.085 us; speedup vs baseline: 1.5076x; 1.1999x over previous
//
#include <hip/hip_runtime.h>

// TensorProductWithScalarComponents: out[s,w',k] = c * sum_{u,v} Wc[(u,v),w'] * x[s,u,k]*y[s,v]
// Wc = Wt . Wl folded on device, packed in MFMA-B fragment order (f16), K-order kc = u*2+vh.
// Staged-GEMM structure: 512-thread blocks (8 waves), all waves share all N-tiles.
// B double-buffered in LDS via global_load_lds (16KB chunks); x reg-staged per 16-u slab;
// y in registers. One barrier per chunk. f16 MFMA 16x16x32; pow2 path-norm in f32 epilogue.

typedef _Float16 f16x8 __attribute__((ext_vector_type(8)));
typedef _Float16 h2    __attribute__((ext_vector_type(2)));
typedef float    f32x4 __attribute__((ext_vector_type(4)));

__device__ __forceinline__ void gload_lds16(const void* g, void* l) {
    __builtin_amdgcn_global_load_lds(
        (const __attribute__((address_space(1))) unsigned*)g,
        (__attribute__((address_space(3))) unsigned*)l, 16, 0, 0);
}

// ---------------- prologue: fold Wl into Wt, pack into MFMA-B fragment layout (f16) ----------
// (kc, nt, lane, j) <-> (u = kc>>1, vh = kc&1, v = vh*32 + (lane>>4)*8 + j, w' = nt*16 + (lane&15))
// stored at Bp[((kc*NT + nt)*64 + lane)*8 + j]   (K-order: u outer, vh inner)
template<int M, int NT>
__global__ void pack_b(const float* __restrict__ Wt, const float* __restrict__ Wl,
                       _Float16* __restrict__ Bp) {
    const int gid = blockIdx.x * 256 + threadIdx.x;
    const int total = M * 64 * M / 2;
    if (gid >= total) return;
    const int w_ = gid & (M - 1);            // output channel w'
    const int uvp = gid / M;                 // uv pair index
    const float4* wtA = (const float4*)(Wt + (size_t)(2 * uvp) * M);
    const float4* wtB = (const float4*)(Wt + (size_t)(2 * uvp + 1) * M);
    float a0 = 0.f, a1 = 0.f;
    #pragma unroll 4
    for (int w = 0; w < M; w += 4) {
        float4 tA = wtA[w >> 2], tB = wtB[w >> 2];
        float l0 = Wl[(w + 0) * M + w_], l1 = Wl[(w + 1) * M + w_];
        float l2 = Wl[(w + 2) * M + w_], l3 = Wl[(w + 3) * M + w_];
        a0 += tA.x * l0 + tA.y * l1 + tA.z * l2 + tA.w * l3;
        a1 += tB.x * l0 + tB.y * l1 + tB.z * l2 + tB.w * l3;
    }
    #pragma unroll
    for (int t = 0; t < 2; ++t) {
        const int uv = 2 * uvp + t;
        const int u = uv >> 6, v = uv & 63;
        const int vh = v >> 5, vv = v & 31, quad = vv >> 3, j = vv & 7;
        const int kc = u * 2 + vh, nt = w_ >> 4, lane = quad * 16 + (w_ & 15);
        Bp[((size_t)(kc * NT + nt) * 64 + lane) * 8 + j] = (_Float16)(t ? a1 : a0);
    }
}

// ---------------- main fused staged GEMM ----------------
template<int M, int NCOMP, int XOFF, int NT, int KC, int MT>
__device__ __forceinline__ void tp_block(char* smem, int wg,
    const float* __restrict__ x, const float* __restrict__ y,
    const _Float16* __restrict__ Bp, float* __restrict__ out, int Rtot, float cscale)
{
    constexpr int WM = MT / 128;          // 8 waves, each WM 16-row frags
    constexpr int WN = NT;                // every wave covers all N-tiles (B shared via LDS)
    constexpr int UC = KC / 2;            // u's per B chunk
    constexpr int XU = 16;                // u's per x slab
    constexpr int KTOT = 2 * M;
    constexpr int NCHUNK = KTOT / KC;
    constexpr int CPS = XU / UC;          // chunks per x slab
    constexpr int NSLAB = M / XU;
    constexpr int BCH = KC * NT * 1024;   // B chunk bytes (=16384 for all three)
    constexpr int XSL = MT * XU * 2;      // x slab bytes
    constexpr int NS_T = MT / NCOMP + 2;  // samples touched by a tile (upper bound)
    constexpr int XE = NS_T * XU * NCOMP; // x elements per slab
    constexpr int XITER = (XE + 511) / 512;

    char* bb0 = smem;
    char* bb1 = smem + BCH;
    char* xb0 = smem + 2 * BCH;
    char* xb1 = smem + 2 * BCH + XSL;

    const int tid = threadIdx.x;
    const int lane = tid & 63;
    const int wv = tid >> 6;
    const int l15 = lane & 15;
    const int quad = lane >> 4;
    const int r0 = wg * MT;
    const int s0 = r0 / NCOMP;
    const int k0 = r0 - s0 * NCOMP;

    float xt[XITER];
    auto xld = [&](int slab) {            // issue x global loads for a slab into registers
        const int ub = slab * XU;
        #pragma unroll
        for (int i = 0; i < XITER; ++i) {
            const int p = tid + i * 512;
            float v = 0.f;
            if (p < XE) {
                const int sl = p / (XU * NCOMP);
                const int fo = p - sl * (XU * NCOMP);
                const int ul = fo / NCOMP;
                const int k  = fo - ul * NCOMP;
                const int rl = sl * NCOMP + k - k0;
                if (rl >= 0 && rl < MT && (r0 + rl) < Rtot)
                    v = x[(size_t)(s0 + sl) * 480 + XOFF + (ub + ul) * NCOMP + k];
            }
            xt[i] = v;
        }
    };
    auto xwr = [&](char* xd) {            // cvt + LDS write (loads have had CPS-1 chunks to land)
        #pragma unroll
        for (int i = 0; i < XITER; ++i) {
            const int p = tid + i * 512;
            if (p < XE) {
                const int sl = p / (XU * NCOMP);
                const int fo = p - sl * (XU * NCOMP);
                const int ul = fo / NCOMP;
                const int k  = fo - ul * NCOMP;
                const int rl = sl * NCOMP + k - k0;
                if (rl >= 0 && rl < MT)
                    *(_Float16*)(xd + (rl * XU + ul) * 2) = (_Float16)xt[i];
            }
        }
    };
    auto stageB = [&](int c, char* bd) {  // 2 x global_load_lds_dwordx4 per wave = 16KB/block
        const char* gs = (const char*)Bp + (size_t)c * BCH + wv * 2048 + lane * 16;
        char* ld = bd + wv * 2048;
        gload_lds16(gs, ld);
        gload_lds16(gs + 1024, ld + 1024);
    };

    // y -> registers once per block (both v-halves), f32 -> packed f16 pairs
    int rowf[WM];
    union YH { f16x8 v; h2 h[4]; };
    YH yh[2][WM];
    #pragma unroll
    for (int f = 0; f < WM; ++f) {
        rowf[f] = wv * (WM * 16) + f * 16 + l15;
        const int Rg = r0 + rowf[f];
        const int sf = (Rg < Rtot) ? (int)((unsigned)Rg / NCOMP) : 0;
        #pragma unroll
        for (int vh = 0; vh < 2; ++vh) {
            const float4* yp = (const float4*)(y + (size_t)sf * 64 + vh * 32 + quad * 8);
            const float4 a = yp[0], b = yp[1];
            union { f16x8 v; _Float16 e[8]; } t;
            t.e[0] = (_Float16)a.x; t.e[1] = (_Float16)a.y;
            t.e[2] = (_Float16)a.z; t.e[3] = (_Float16)a.w;
            t.e[4] = (_Float16)b.x; t.e[5] = (_Float16)b.y;
            t.e[6] = (_Float16)b.z; t.e[7] = (_Float16)b.w;
            yh[vh][f].v = t.v;
        }
    }

    f32x4 acc[WM][WN];
    #pragma unroll
    for (int f = 0; f < WM; ++f)
        #pragma unroll
        for (int g = 0; g < WN; ++g) acc[f][g] = f32x4{0.f, 0.f, 0.f, 0.f};

    // prologue: slab 0 + chunk 0
    xld(0);
    stageB(0, bb0);
    xwr(xb0);
    __syncthreads();

    int bcur = 0, xcur = 0;
    #pragma unroll 1
    for (int c = 0; c < NCHUNK; ++c) {
        if (c + 1 < NCHUNK) stageB(c + 1, bcur ? bb0 : bb1);
        const int cm = c & (CPS - 1);
        const int sl1 = c / CPS + 1;
        if (cm == 0 && sl1 < NSLAB) xld(sl1);

        const char* bs = bcur ? bb1 : bb0;
        const char* xs = xcur ? xb1 : xb0;
        const int uoff = cm * UC;
        unsigned xv0[WM], xv1[WM];
        #pragma unroll
        for (int f = 0; f < WM; ++f) {
            const char* xa = xs + (rowf[f] * XU + uoff) * 2;
            if constexpr (UC == 1)      xv0[f] = *(const unsigned short*)xa;
            else if constexpr (UC == 2) xv0[f] = *(const unsigned*)xa;
            else { const uint2 t = *(const uint2*)xa; xv0[f] = t.x; xv1[f] = t.y; }
        }
        #pragma unroll
        for (int kl = 0; kl < KC; ++kl) {
            const int vh = kl & 1, uo = kl >> 1;
            f16x8 bg[WN];
            #pragma unroll
            for (int g = 0; g < WN; ++g)
                bg[g] = *(const f16x8*)(bs + (kl * NT + g) * 1024 + lane * 16);
            f16x8 af[WM];
            #pragma unroll
            for (int f = 0; f < WM; ++f) {
                const unsigned d = (UC == 4 && (uo & 2)) ? xv1[f] : xv0[f];
                const unsigned hh = (uo & 1) ? (d >> 16) : (d & 0xffffu);
                union { unsigned u; h2 h; } xb2; xb2.u = hh | (hh << 16);
                union { f16x8 v; h2 h[4]; } a_;
                #pragma unroll
                for (int q = 0; q < 4; ++q) a_.h[q] = xb2.h * yh[vh][f].h[q];
                af[f] = a_.v;
            }
            #pragma unroll
            for (int f = 0; f < WM; ++f)
                #pragma unroll
                for (int g = 0; g < WN; ++g)
                    acc[f][g] = __builtin_amdgcn_mfma_f32_16x16x32_f16(af[f], bg[g], acc[f][g], 0, 0, 0);
        }
        if (cm == CPS - 1 && sl1 < NSLAB) xwr(xcur ? xb0 : xb1);
        __syncthreads();
        bcur ^= 1;
        if (cm == CPS - 1) xcur ^= 1;
    }

    // epilogue: C/D layout col = lane&15, row = quad*4 + reg (m89-verified); pow2 scale in f32
    #pragma unroll
    for (int f = 0; f < WM; ++f) {
        #pragma unroll
        for (int g = 0; g < WN; ++g) {
            const int col = g * 16 + l15;   // w'
            #pragma unroll
            for (int r = 0; r < 4; ++r) {
                const int R = r0 + wv * (WM * 16) + f * 16 + quad * 4 + r;
                if (R < Rtot) {
                    const int s = (int)((unsigned)R / NCOMP);
                    const int k = R - s * NCOMP;
                    out[(size_t)s * 480 + XOFF + col * NCOMP + k] = acc[f][g][r] * cscale;
                }
            }
        }
    }
}

__global__ __launch_bounds__(512, 2)
void tp_main(const float* __restrict__ x, const float* __restrict__ y,
             const _Float16* __restrict__ B0, const _Float16* __restrict__ B1,
             const _Float16* __restrict__ B2, float* __restrict__ out,
             int R0, int R1, int R2, int G0, int G1)
{
    // LDS: B 2x16KB + x 2x(MT*16*2): l0 = 57344, l1 = 65536, l2 = 65536
    __shared__ char smem[65536];
    const int b = blockIdx.x;
    if (b < G0)            tp_block<128, 1,   0, 8, 2, 384>(smem, b,           x, y, B0, out, R0, 1.f / 1024.f);
    else if (b < G0 + G1)  tp_block< 64, 3, 128, 4, 4, 512>(smem, b - G0,      x, y, B1, out, R1, 1.f / 512.f);
    else                   tp_block< 32, 5, 320, 2, 8, 512>(smem, b - G0 - G1, x, y, B2, out, R2, 1.f / 256.f);
}

extern "C" void kernel_launch(void* const* d_in, const int* in_sizes, int n_in,
                              void* d_out, int out_size, void* d_ws, size_t ws_size,
                              hipStream_t stream) {
    const float* x   = (const float*)d_in[0];
    const float* y   = (const float*)d_in[1];
    const float* Wt0 = (const float*)d_in[2];
    const float* Wl0 = (const float*)d_in[3];
    const float* Wt1 = (const float*)d_in[4];
    const float* Wl1 = (const float*)d_in[5];
    const float* Wt2 = (const float*)d_in[6];
    const float* Wl2 = (const float*)d_in[7];
    float* out = (float*)d_out;

    const int Ns = in_sizes[0] / 480;

    _Float16* B0 = (_Float16*)d_ws;                    // 8192x128 f16 = 2 MiB
    _Float16* B1 = B0 + 8192 * 128;                    // 4096x64  = 512 KiB
    _Float16* B2 = B1 + 4096 * 64;                     // 2048x32  = 128 KiB

    pack_b<128, 8><<<(128 * 64 * 128 / 2 + 255) / 256, 256, 0, stream>>>(Wt0, Wl0, B0);
    pack_b< 64, 4><<<( 64 * 64 *  64 / 2 + 255) / 256, 256, 0, stream>>>(Wt1, Wl1, B1);
    pack_b< 32, 2><<<( 32 * 64 *  32 / 2 + 255) / 256, 256, 0, stream>>>(Wt2, Wl2, B2);

    const int R0 = Ns, R1 = Ns * 3, R2 = Ns * 5;
    const int G0 = (R0 + 383) / 384;
    const int G1 = (R1 + 511) / 512;
    const int G2 = (R2 + 511) / 512;
    tp_main<<<G0 + G1 + G2, 512, 0, stream>>>(x, y, B0, B1, B2, out, R0, R1, R2, G0, G1);
}